// Round 3
// baseline (6931.295 us; speedup 1.0000x reference)
//
#include <hip/hip_runtime.h>

// EGA layer (GAT-like, GLOBAL per-head softmax over edges) on MI355X.
// Round 3: bf16x3-split MFMA GEMM (K'=768, one fused bf16 GEMM), scores fused
// into GEMM epilogue, Wh never materialized -- surviving edges (~500 of 800K,
// global softmax concentration) get Wh[col] recomputed exactly in pass2.
//
// Accuracy: x=xh+xl, W=Wh+Wl (bf16 RNE). xh*Wh + xl*Wh + xh*Wl leaves only the
// xl*Wl term (~|x||W|*2^-18 ~ 2.4e-7/term, ~4e-6 after K=256 random-sign sum).
// MFMA accumulates fp32 -> effectively fp32-quality Wh/scores.

#define N_NODES  50000
#define N_EDGES  800000
#define IN_DIM   256
#define OUT_DIM  64
#define HEADS    8
#define NCOL     512
#define KP       768                 // split K' = 3*256
#define NBLK_RED 1024
#define LN_W_EPS (-20.72326584f)     // ln(1e-9) skip threshold

typedef __bf16 bf16x8 __attribute__((ext_vector_type(8)));
typedef float  f32x4  __attribute__((ext_vector_type(4)));

__device__ __forceinline__ short f2bf(float f) {     // RNE float->bf16 bits
    unsigned u = __builtin_bit_cast(unsigned, f);
    u += 0x7fffu + ((u >> 16) & 1u);
    return (short)(u >> 16);
}
__device__ __forceinline__ float bf2f(short s) {
    unsigned u = ((unsigned)(unsigned short)s) << 16;
    return __builtin_bit_cast(float, u);
}

// ---------------------------------------------------------------------------
// split x -> A2[row][0:256]=bf16(x) (hi), A2[row][256:512]=bf16(x-hi) (lo)
// ---------------------------------------------------------------------------
__global__ __launch_bounds__(256) void split_kernel(
    const float* __restrict__ x, short* __restrict__ A2)
{
    const int g   = blockIdx.x * 256 + threadIdx.x;  // 50000*64 exact
    const int row = g >> 6;
    const int j4  = (g & 63) * 4;
    const float4 v = *(const float4*)(x + (size_t)row * IN_DIM + j4);
    short4 hi, lo;
    hi.x = f2bf(v.x); lo.x = f2bf(v.x - bf2f(hi.x));
    hi.y = f2bf(v.y); lo.y = f2bf(v.y - bf2f(hi.y));
    hi.z = f2bf(v.z); lo.z = f2bf(v.z - bf2f(hi.z));
    hi.w = f2bf(v.w); lo.w = f2bf(v.w - bf2f(hi.w));
    *(short4*)(A2 + (size_t)row * 512 + j4)       = hi;
    *(short4*)(A2 + (size_t)row * 512 + 256 + j4) = lo;
}

// ---------------------------------------------------------------------------
// Build Bt[n][k'] (n-major, 512 x 768 bf16): rows of B' = [Wh; Wh; Wl]
//   k'<256: Wh[k'][n] ; 256..511: Wh[k'-256][n] (pairs with xl) ;
//   512..767: Wl[k'-512][n] (pairs with xh).  n = h*64+o, W[h][d][o].
// Also zero-inits the pass1 edge counter.
// ---------------------------------------------------------------------------
__global__ void wprep_kernel(const float* __restrict__ W,
                             short* __restrict__ Bt, int* __restrict__ cnt)
{
    const int g = blockIdx.x * 256 + threadIdx.x;   // 512*256 exact
    if (g == 0) *cnt = 0;
    const int n = g >> 8, d = g & 255;
    const int h = n >> 6, o = n & 63;
    const float w = W[((size_t)h * IN_DIM + d) * OUT_DIM + o];
    const short hi = f2bf(w);
    const short lo = f2bf(w - bf2f(hi));
    Bt[(size_t)n * KP + d]       = hi;
    Bt[(size_t)n * KP + 256 + d] = hi;
    Bt[(size_t)n * KP + 512 + d] = lo;
}

// ---------------------------------------------------------------------------
// MFMA GEMM, 128x128 tile, BK=64, 16x16x32 bf16, 4 waves (2x2), 4x4 mfma/wave.
// Outputs ONLY the fused scores s_src/s_dst (Wh itself is never stored).
// A k-mapping: k<512 -> A2 col k ([xh|xl]); k>=512 -> col k-512 (xh again).
// LDS rows padded to 72 shorts (144 B, 16B-aligned, bank stride 4).
// ---------------------------------------------------------------------------
__global__ __launch_bounds__(256) void gemm_kernel(
    const short* __restrict__ A2, const short* __restrict__ Bt,
    const float* __restrict__ b, const float* __restrict__ a,
    float* __restrict__ s_src, float* __restrict__ s_dst)
{
    __shared__ __align__(16) short As[128 * 72];
    __shared__ __align__(16) short Bs[128 * 72];

    const int tid  = threadIdx.x;
    const int row0 = blockIdx.y * 128;
    const int n0   = blockIdx.x * 128;
    const int wave = tid >> 6, lane = tid & 63;
    const int wm = wave >> 1, wn = wave & 1;
    const int cl = lane & 15, quad = lane >> 4;

    f32x4 acc[4][4] = {};

    for (int k0 = 0; k0 < KP; k0 += 64) {
        const int ka = (k0 < 512) ? k0 : k0 - 512;
        int4 av[4], bv[4];
        #pragma unroll
        for (int t = 0; t < 4; ++t) {
            const int c  = tid + t * 256;       // 1024 chunks of 8 bf16
            const int r  = c >> 3;
            const int o8 = (c & 7) * 8;
            int ra = row0 + r; if (ra > N_NODES - 1) ra = N_NODES - 1;
            av[t] = *(const int4*)(A2 + (size_t)ra * 512 + ka + o8);
            bv[t] = *(const int4*)(Bt + (size_t)(n0 + r) * KP + k0 + o8);
        }
        __syncthreads();                         // protect prior LDS reads
        #pragma unroll
        for (int t = 0; t < 4; ++t) {
            const int c  = tid + t * 256;
            const int r  = c >> 3;
            const int o8 = (c & 7) * 8;
            *(int4*)(&As[r * 72 + o8]) = av[t];
            *(int4*)(&Bs[r * 72 + o8]) = bv[t];
        }
        __syncthreads();
        #pragma unroll
        for (int ks = 0; ks < 64; ks += 32) {
            bf16x8 af[4], bf[4];
            #pragma unroll
            for (int i = 0; i < 4; ++i)
                af[i] = *(const bf16x8*)(&As[(wm * 64 + i * 16 + cl) * 72 + ks + quad * 8]);
            #pragma unroll
            for (int j = 0; j < 4; ++j)
                bf[j] = *(const bf16x8*)(&Bs[(wn * 64 + j * 16 + cl) * 72 + ks + quad * 8]);
            #pragma unroll
            for (int i = 0; i < 4; ++i)
                #pragma unroll
                for (int j = 0; j < 4; ++j)
                    acc[i][j] = __builtin_amdgcn_mfma_f32_16x16x32_bf16(
                        af[i], bf[j], acc[i][j], 0, 0, 0);
        }
    }

    // Epilogue: wave covers 64 cols == one head. C/D: col=lane&15, row=quad*4+r.
    const int h = blockIdx.x * 2 + wn;
    float bsv[4], asv[4], adv[4];
    #pragma unroll
    for (int j = 0; j < 4; ++j) {
        const int cc = j * 16 + cl;
        bsv[j] = b[h * 64 + cc];
        asv[j] = a[h * 128 + cc];
        adv[j] = a[h * 128 + 64 + cc];
    }
    #pragma unroll
    for (int i = 0; i < 4; ++i) {
        #pragma unroll
        for (int r = 0; r < 4; ++r) {
            float ps = 0.f, pd = 0.f;
            #pragma unroll
            for (int j = 0; j < 4; ++j) {
                const float o = acc[i][j][r] + bsv[j];
                ps += o * asv[j];
                pd += o * adv[j];
            }
            #pragma unroll
            for (int m = 1; m < 16; m <<= 1) {
                ps += __shfl_xor(ps, m);
                pd += __shfl_xor(pd, m);
            }
            const int row = row0 + wm * 64 + i * 16 + quad * 4 + r;
            if (cl == 0 && row < N_NODES) {
                s_src[row * 8 + h] = ps;
                s_dst[row * 8 + h] = pd;
            }
        }
    }
}

// ---------------------------------------------------------------------------
// Online (max, sumexp) over all edges per head. Per-block partials.
// ---------------------------------------------------------------------------
__global__ __launch_bounds__(256) void edge_reduce_kernel(
    const int* __restrict__ ei, const float* __restrict__ s_src,
    const float* __restrict__ s_dst, float* __restrict__ partial)
{
    float m[8], l[8];
    #pragma unroll
    for (int h = 0; h < 8; ++h) { m[h] = -1e30f; l[h] = 0.f; }

    for (int e = blockIdx.x * 256 + threadIdx.x; e < N_EDGES; e += gridDim.x * 256) {
        const int row = ei[e];
        const int col = ei[N_EDGES + e];
        const float4 s0 = *(const float4*)(s_src + row * 8);
        const float4 s1 = *(const float4*)(s_src + row * 8 + 4);
        const float4 d0 = *(const float4*)(s_dst + col * 8);
        const float4 d1 = *(const float4*)(s_dst + col * 8 + 4);
        const float ev[8] = { s0.x + d0.x, s0.y + d0.y, s0.z + d0.z, s0.w + d0.w,
                              s1.x + d1.x, s1.y + d1.y, s1.z + d1.z, s1.w + d1.w };
        #pragma unroll
        for (int h = 0; h < 8; ++h) {
            float t = ev[h];
            t = t > 0.f ? t : 0.01f * t;     // leaky_relu 0.01
            if (t > m[h]) { l[h] = l[h] * __expf(m[h] - t) + 1.f; m[h] = t; }
            else          { l[h] += __expf(t - m[h]); }
        }
    }

    __shared__ float red[16][256];
    const int tid = threadIdx.x;
    #pragma unroll
    for (int h = 0; h < 8; ++h) { red[h][tid] = m[h]; red[8 + h][tid] = l[h]; }
    __syncthreads();
    for (int s = 128; s > 0; s >>= 1) {
        if (tid < s) {
            #pragma unroll
            for (int h = 0; h < 8; ++h) {
                float mo = red[h][tid + s], lo = red[8 + h][tid + s];
                float mm = red[h][tid],     ll = red[8 + h][tid];
                if (mo > mm) { ll = ll * __expf(mm - mo) + lo; mm = mo; }
                else         { ll += lo * __expf(mo - mm); }
                red[h][tid] = mm; red[8 + h][tid] = ll;
            }
        }
        __syncthreads();
    }
    if (tid == 0) {
        #pragma unroll
        for (int h = 0; h < 8; ++h) {
            partial[blockIdx.x * 16 + h]     = red[h][0];
            partial[blockIdx.x * 16 + 8 + h] = red[8 + h][0];
        }
    }
}

// ---------------------------------------------------------------------------
// Merge partials. coef[h]=M_h, coef[8+h]=g_h/L_h, coef[16+h]=skip cutoff.
// ---------------------------------------------------------------------------
__global__ void finalize_kernel(const float* __restrict__ partial,
                                const float* __restrict__ gate,
                                float* __restrict__ coef, int nblk)
{
    const int t = threadIdx.x;           // 64 threads: h = t&7, chunk j = t>>3
    const int h = t & 7;
    const int j = t >> 3;
    float m = -1e30f, l = 0.f;
    for (int bk = j; bk < nblk; bk += 8) {
        const float mb = partial[bk * 16 + h];
        const float lb = partial[bk * 16 + 8 + h];
        if (mb > m) { l = l * __expf(m - mb) + lb; m = mb; }
        else        { l += lb * __expf(mb - m); }
    }
    #pragma unroll
    for (int s = 8; s < 64; s <<= 1) {
        const float mo = __shfl_xor(m, s);
        const float lo = __shfl_xor(l, s);
        if (mo > m) { l = l * __expf(m - mo) + lo; m = mo; }
        else        { l += lo * __expf(mo - m); }
    }
    if (j == 0) {
        float gm = gate[0];
        for (int i = 1; i < 8; ++i) gm = fmaxf(gm, gate[i]);
        float gs = 0.f;
        for (int i = 0; i < 8; ++i) gs += __expf(gate[i] - gm);
        const float g = __expf(gate[h] - gm) / gs;
        const float C = g / l;
        coef[h]      = m;
        coef[8 + h]  = C;
        coef[16 + h] = m + LN_W_EPS - __logf(C);   // t >= cut  <=>  w >= eps
    }
}

// ---------------------------------------------------------------------------
// Pass 1: threshold test, append surviving edge ids to list.
// ---------------------------------------------------------------------------
__global__ __launch_bounds__(256) void pass1_kernel(
    const int* __restrict__ ei, const float* __restrict__ s_src,
    const float* __restrict__ s_dst, const float* __restrict__ coef,
    int* __restrict__ cnt, int* __restrict__ list)
{
    __shared__ float cCut[8];
    if (threadIdx.x < 8) cCut[threadIdx.x] = coef[16 + threadIdx.x];
    __syncthreads();

    const int e = blockIdx.x * 256 + threadIdx.x;
    if (e >= N_EDGES) return;
    const int row = ei[e];
    const int col = ei[N_EDGES + e];
    const float4 s0 = *(const float4*)(s_src + row * 8);
    const float4 s1 = *(const float4*)(s_src + row * 8 + 4);
    const float4 d0 = *(const float4*)(s_dst + col * 8);
    const float4 d1 = *(const float4*)(s_dst + col * 8 + 4);
    float t[8] = { s0.x + d0.x, s0.y + d0.y, s0.z + d0.z, s0.w + d0.w,
                   s1.x + d1.x, s1.y + d1.y, s1.z + d1.z, s1.w + d1.w };
    bool pass = false;
    #pragma unroll
    for (int h = 0; h < 8; ++h) {
        t[h] = t[h] > 0.f ? t[h] : 0.01f * t[h];
        pass |= (t[h] >= cCut[h]);
    }
    if (pass) {
        const int idx = atomicAdd(cnt, 1);
        if (idx < N_EDGES) list[idx] = e;     // full-capacity list: never drops
    }
}

// ---------------------------------------------------------------------------
// Pass 2: one block per surviving edge. Recompute Wh[col][:] exactly (same
// bf16x3 split, fp32 accumulate), weight by w_h, atomicAdd into out[row].
// ---------------------------------------------------------------------------
__global__ __launch_bounds__(256) void pass2_kernel(
    const int* __restrict__ list, const int* __restrict__ cnt,
    const int* __restrict__ ei, const float* __restrict__ s_src,
    const float* __restrict__ s_dst, const short* __restrict__ A2,
    const short* __restrict__ Bt, const float* __restrict__ b,
    const float* __restrict__ coef, float* __restrict__ out)
{
    __shared__ short a2s[512];
    __shared__ float wsh[8];
    const int t = threadIdx.x;
    int n = *cnt; if (n > N_EDGES) n = N_EDGES;

    for (int i = blockIdx.x; i < n; i += gridDim.x) {
        const int e   = list[i];
        const int row = ei[e];
        const int col = ei[N_EDGES + e];
        a2s[t]       = A2[(size_t)col * 512 + t];
        a2s[256 + t] = A2[(size_t)col * 512 + 256 + t];
        if (t < 8) {
            float th = s_src[row * 8 + t] + s_dst[col * 8 + t];
            th = th > 0.f ? th : 0.01f * th;
            wsh[t] = __expf(th - coef[t]) * coef[8 + t];
        }
        __syncthreads();

        float v = 0.f;
        #pragma unroll
        for (int cc = 0; cc < 2; ++cc) {
            const int c = t + cc * 256;
            const short* bt = Bt + (size_t)c * KP;
            float s = b[c];                      // bias: Wh = x·W + b
            for (int k = 0; k < 256; ++k) {
                const float ah = bf2f(a2s[k]);
                s += ah * bf2f(bt[k]);                       // xh*Wh
                s += bf2f(a2s[256 + k]) * bf2f(bt[256 + k]); // xl*Wh
                s += ah * bf2f(bt[512 + k]);                 // xh*Wl
            }
            v += wsh[c >> 6] * s;
        }
        atomicAdd(out + (size_t)row * OUT_DIM + (t & 63), v);
        __syncthreads();
    }
}

// ---------------------------------------------------------------------------
extern "C" void kernel_launch(void* const* d_in, const int* in_sizes, int n_in,
                              void* d_out, int out_size, void* d_ws, size_t ws_size,
                              hipStream_t stream)
{
    const float* x    = (const float*)d_in[0];
    const int*   ei   = (const int*)  d_in[1];
    const float* W    = (const float*)d_in[2];
    const float* b    = (const float*)d_in[3];
    const float* a    = (const float*)d_in[4];
    const float* gate = (const float*)d_in[5];
    float* out = (float*)d_out;

    // workspace layout (bytes, all 16B-aligned), total ~58.5 MB
    char* wsb = (char*)d_ws;
    short* A2      = (short*)(wsb);                 // 50000*512*2 = 51,200,000
    short* Bt      = (short*)(wsb + 51200000);      // 512*768*2   =    786,432
    float* s_src   = (float*)(wsb + 51986432);      // 1,600,000
    float* s_dst   = (float*)(wsb + 53586432);      // 1,600,000
    float* partial = (float*)(wsb + 55186432);      //    65,536
    float* coef    = (float*)(wsb + 55251968);      //       128 (pad)
    int*   cnt     = (int*)  (wsb + 55252096);      //        16 (pad)
    int*   list    = (int*)  (wsb + 55252112);      // 3,200,000

    hipMemsetAsync(d_out, 0, (size_t)N_NODES * OUT_DIM * sizeof(float), stream);

    split_kernel<<<(N_NODES * 64) / 256, 256, 0, stream>>>(x, A2);
    wprep_kernel<<<512, 256, 0, stream>>>(W, Bt, cnt);

    gemm_kernel<<<dim3(4, (N_NODES + 127) / 128), 256, 0, stream>>>(
        A2, Bt, b, a, s_src, s_dst);

    edge_reduce_kernel<<<NBLK_RED, 256, 0, stream>>>(ei, s_src, s_dst, partial);
    finalize_kernel<<<1, 64, 0, stream>>>(partial, gate, coef, NBLK_RED);

    pass1_kernel<<<(N_EDGES + 255) / 256, 256, 0, stream>>>(
        ei, s_src, s_dst, coef, cnt, list);
    pass2_kernel<<<1024, 256, 0, stream>>>(
        list, cnt, ei, s_src, s_dst, A2, Bt, b, coef, out);
}

// Round 4
// 394.350 us; speedup vs baseline: 17.5765x; 17.5765x over previous
//
#include <hip/hip_runtime.h>

// EGA layer (GAT-like, GLOBAL per-head softmax over edges) on MI355X.
// Round 4: bf16x3-split MFMA GEMM (K'=768) with fused score epilogue AND
// materialized f32 Wh (102 MB); thresholded ballot scatter over the ~40K
// edges whose softmax weight >= 1e-9 (measured via R3 WRITE_SIZE: ~37K rows).
// R3's pass2 (recompute-Wh-per-edge) was latency-bound at 6.6ms -- reverted.
//
// Accuracy: x=xh+xl, W=Wh+Wl (bf16 RNE). xh*Wh + xl*Wh + xh*Wl leaves only
// xl*Wl (~4e-6). MFMA accumulates fp32 -> fp32-quality Wh and scores.

#define N_NODES  50000
#define N_EDGES  800000
#define IN_DIM   256
#define OUT_DIM  64
#define HEADS    8
#define NCOL     512
#define KP       768                 // split K' = 3*256
#define NBLK_RED 1024
#define LN_W_EPS (-20.72326584f)     // ln(1e-9) skip threshold

typedef __bf16 bf16x8 __attribute__((ext_vector_type(8)));
typedef float  f32x4  __attribute__((ext_vector_type(4)));

__device__ __forceinline__ short f2bf(float f) {     // RNE float->bf16 bits
    unsigned u = __builtin_bit_cast(unsigned, f);
    u += 0x7fffu + ((u >> 16) & 1u);
    return (short)(u >> 16);
}
__device__ __forceinline__ float bf2f(short s) {
    unsigned u = ((unsigned)(unsigned short)s) << 16;
    return __builtin_bit_cast(float, u);
}

// ---------------------------------------------------------------------------
// split x -> A2[row][0:256]=bf16(x) (hi), A2[row][256:512]=bf16(x-hi) (lo)
// ---------------------------------------------------------------------------
__global__ __launch_bounds__(256) void split_kernel(
    const float* __restrict__ x, short* __restrict__ A2)
{
    const int g   = blockIdx.x * 256 + threadIdx.x;  // 50000*64 exact
    const int row = g >> 6;
    const int j4  = (g & 63) * 4;
    const float4 v = *(const float4*)(x + (size_t)row * IN_DIM + j4);
    short4 hi, lo;
    hi.x = f2bf(v.x); lo.x = f2bf(v.x - bf2f(hi.x));
    hi.y = f2bf(v.y); lo.y = f2bf(v.y - bf2f(hi.y));
    hi.z = f2bf(v.z); lo.z = f2bf(v.z - bf2f(hi.z));
    hi.w = f2bf(v.w); lo.w = f2bf(v.w - bf2f(hi.w));
    *(short4*)(A2 + (size_t)row * 512 + j4)       = hi;
    *(short4*)(A2 + (size_t)row * 512 + 256 + j4) = lo;
}

// ---------------------------------------------------------------------------
// Build Bt[n][k'] (n-major, 512 x 768 bf16): rows of B' = [Wh; Wh; Wl]
// ---------------------------------------------------------------------------
__global__ void wprep_kernel(const float* __restrict__ W, short* __restrict__ Bt)
{
    const int g = blockIdx.x * 256 + threadIdx.x;   // 512*256 exact
    const int n = g >> 8, d = g & 255;
    const int h = n >> 6, o = n & 63;
    const float w = W[((size_t)h * IN_DIM + d) * OUT_DIM + o];
    const short hi = f2bf(w);
    const short lo = f2bf(w - bf2f(hi));
    Bt[(size_t)n * KP + d]       = hi;
    Bt[(size_t)n * KP + 256 + d] = hi;
    Bt[(size_t)n * KP + 512 + d] = lo;
}

// ---------------------------------------------------------------------------
// MFMA GEMM, 128x128 tile, BK=64, 16x16x32 bf16, 4 waves (2x2), 4x4 mfma/wave.
// Epilogue stores f32 Wh AND the fused scores s_src/s_dst.
// LDS rows padded to 72 shorts (144 B): fragment-read bank aliasing is 2-way
// (free, m136); global_load_lds is incompatible with the pad (m104).
// ---------------------------------------------------------------------------
__global__ __launch_bounds__(256) void gemm_kernel(
    const short* __restrict__ A2, const short* __restrict__ Bt,
    const float* __restrict__ b, const float* __restrict__ a,
    float* __restrict__ Wh, float* __restrict__ s_src, float* __restrict__ s_dst)
{
    __shared__ __align__(16) short As[128 * 72];
    __shared__ __align__(16) short Bs[128 * 72];

    const int tid  = threadIdx.x;
    const int row0 = blockIdx.y * 128;
    const int n0   = blockIdx.x * 128;
    const int wave = tid >> 6, lane = tid & 63;
    const int wm = wave >> 1, wn = wave & 1;
    const int cl = lane & 15, quad = lane >> 4;

    f32x4 acc[4][4] = {};

    for (int k0 = 0; k0 < KP; k0 += 64) {
        const int ka = (k0 < 512) ? k0 : k0 - 512;   // [xh|xl|xh] k-mapping
        int4 av[4], bv[4];
        #pragma unroll
        for (int t = 0; t < 4; ++t) {
            const int c  = tid + t * 256;       // 1024 chunks of 8 bf16
            const int r  = c >> 3;
            const int o8 = (c & 7) * 8;
            int ra = row0 + r; if (ra > N_NODES - 1) ra = N_NODES - 1;
            av[t] = *(const int4*)(A2 + (size_t)ra * 512 + ka + o8);
            bv[t] = *(const int4*)(Bt + (size_t)(n0 + r) * KP + k0 + o8);
        }
        __syncthreads();                         // protect prior LDS reads
        #pragma unroll
        for (int t = 0; t < 4; ++t) {
            const int c  = tid + t * 256;
            const int r  = c >> 3;
            const int o8 = (c & 7) * 8;
            *(int4*)(&As[r * 72 + o8]) = av[t];
            *(int4*)(&Bs[r * 72 + o8]) = bv[t];
        }
        __syncthreads();
        #pragma unroll
        for (int ks = 0; ks < 64; ks += 32) {
            bf16x8 af[4], bf[4];
            #pragma unroll
            for (int i = 0; i < 4; ++i)
                af[i] = *(const bf16x8*)(&As[(wm * 64 + i * 16 + cl) * 72 + ks + quad * 8]);
            #pragma unroll
            for (int j = 0; j < 4; ++j)
                bf[j] = *(const bf16x8*)(&Bs[(wn * 64 + j * 16 + cl) * 72 + ks + quad * 8]);
            #pragma unroll
            for (int i = 0; i < 4; ++i)
                #pragma unroll
                for (int j = 0; j < 4; ++j)
                    acc[i][j] = __builtin_amdgcn_mfma_f32_16x16x32_bf16(
                        af[i], bf[j], acc[i][j], 0, 0, 0);
        }
    }

    // Epilogue. Wave covers one head (64 cols). C/D: col=lane&15, row=quad*4+r.
    const int h = blockIdx.x * 2 + wn;
    float bsv[4], asv[4], adv[4];
    #pragma unroll
    for (int j = 0; j < 4; ++j) {
        const int cc = j * 16 + cl;
        bsv[j] = b[h * 64 + cc];
        asv[j] = a[h * 128 + cc];
        adv[j] = a[h * 128 + 64 + cc];
    }
    #pragma unroll
    for (int i = 0; i < 4; ++i) {
        #pragma unroll
        for (int r = 0; r < 4; ++r) {
            const int row = row0 + wm * 64 + i * 16 + quad * 4 + r;
            const bool ok = (row < N_NODES);
            float ps = 0.f, pd = 0.f;
            #pragma unroll
            for (int j = 0; j < 4; ++j) {
                const float o = acc[i][j][r] + bsv[j];
                if (ok)
                    Wh[(size_t)row * NCOL + h * 64 + j * 16 + cl] = o;
                ps += o * asv[j];
                pd += o * adv[j];
            }
            #pragma unroll
            for (int m = 1; m < 16; m <<= 1) {
                ps += __shfl_xor(ps, m);
                pd += __shfl_xor(pd, m);
            }
            if (cl == 0 && ok) {
                s_src[row * 8 + h] = ps;
                s_dst[row * 8 + h] = pd;
            }
        }
    }
}

// ---------------------------------------------------------------------------
// Online (max, sumexp) over all edges per head. Per-block partials.
// ---------------------------------------------------------------------------
__global__ __launch_bounds__(256) void edge_reduce_kernel(
    const int* __restrict__ ei, const float* __restrict__ s_src,
    const float* __restrict__ s_dst, float* __restrict__ partial)
{
    float m[8], l[8];
    #pragma unroll
    for (int h = 0; h < 8; ++h) { m[h] = -1e30f; l[h] = 0.f; }

    for (int e = blockIdx.x * 256 + threadIdx.x; e < N_EDGES; e += gridDim.x * 256) {
        const int row = ei[e];
        const int col = ei[N_EDGES + e];
        const float4 s0 = *(const float4*)(s_src + row * 8);
        const float4 s1 = *(const float4*)(s_src + row * 8 + 4);
        const float4 d0 = *(const float4*)(s_dst + col * 8);
        const float4 d1 = *(const float4*)(s_dst + col * 8 + 4);
        const float ev[8] = { s0.x + d0.x, s0.y + d0.y, s0.z + d0.z, s0.w + d0.w,
                              s1.x + d1.x, s1.y + d1.y, s1.z + d1.z, s1.w + d1.w };
        #pragma unroll
        for (int h = 0; h < 8; ++h) {
            float t = ev[h];
            t = t > 0.f ? t : 0.01f * t;     // leaky_relu 0.01
            if (t > m[h]) { l[h] = l[h] * __expf(m[h] - t) + 1.f; m[h] = t; }
            else          { l[h] += __expf(t - m[h]); }
        }
    }

    __shared__ float red[16][256];
    const int tid = threadIdx.x;
    #pragma unroll
    for (int h = 0; h < 8; ++h) { red[h][tid] = m[h]; red[8 + h][tid] = l[h]; }
    __syncthreads();
    for (int s = 128; s > 0; s >>= 1) {
        if (tid < s) {
            #pragma unroll
            for (int h = 0; h < 8; ++h) {
                float mo = red[h][tid + s], lo = red[8 + h][tid + s];
                float mm = red[h][tid],     ll = red[8 + h][tid];
                if (mo > mm) { ll = ll * __expf(mm - mo) + lo; mm = mo; }
                else         { ll += lo * __expf(mo - mm); }
                red[h][tid] = mm; red[8 + h][tid] = ll;
            }
        }
        __syncthreads();
    }
    if (tid == 0) {
        #pragma unroll
        for (int h = 0; h < 8; ++h) {
            partial[blockIdx.x * 16 + h]     = red[h][0];
            partial[blockIdx.x * 16 + 8 + h] = red[8 + h][0];
        }
    }
}

// ---------------------------------------------------------------------------
// Merge partials. coef[h]=M_h, coef[8+h]=g_h/L_h, coef[16+h]=skip cutoff.
// ---------------------------------------------------------------------------
__global__ void finalize_kernel(const float* __restrict__ partial,
                                const float* __restrict__ gate,
                                float* __restrict__ coef, int nblk)
{
    const int t = threadIdx.x;           // 64 threads: h = t&7, chunk j = t>>3
    const int h = t & 7;
    const int j = t >> 3;
    float m = -1e30f, l = 0.f;
    for (int bk = j; bk < nblk; bk += 8) {
        const float mb = partial[bk * 16 + h];
        const float lb = partial[bk * 16 + 8 + h];
        if (mb > m) { l = l * __expf(m - mb) + lb; m = mb; }
        else        { l += lb * __expf(mb - m); }
    }
    #pragma unroll
    for (int s = 8; s < 64; s <<= 1) {
        const float mo = __shfl_xor(m, s);
        const float lo = __shfl_xor(l, s);
        if (mo > m) { l = l * __expf(m - mo) + lo; m = mo; }
        else        { l += lo * __expf(mo - m); }
    }
    if (j == 0) {
        float gm = gate[0];
        for (int i = 1; i < 8; ++i) gm = fmaxf(gm, gate[i]);
        float gs = 0.f;
        for (int i = 0; i < 8; ++i) gs += __expf(gate[i] - gm);
        const float g = __expf(gate[h] - gm) / gs;
        const float C = g / l;
        coef[h]      = m;
        coef[8 + h]  = C;
        coef[16 + h] = m + LN_W_EPS - __logf(C);   // t >= cut  <=>  w >= eps
    }
}

// ---------------------------------------------------------------------------
// Thresholded scatter (R2-proven). One thread per edge for the score test;
// passing edges processed wave-cooperatively (lane = output dim o).
// ---------------------------------------------------------------------------
__global__ __launch_bounds__(256) void scatter_kernel(
    const int* __restrict__ ei, const float* __restrict__ s_src,
    const float* __restrict__ s_dst, const float* __restrict__ Wh,
    const float* __restrict__ coef, float* __restrict__ out)
{
    __shared__ float cM[8], cC[8], cCut[8];
    if (threadIdx.x < 8)       cM[threadIdx.x]        = coef[threadIdx.x];
    else if (threadIdx.x < 16) cC[threadIdx.x - 8]    = coef[threadIdx.x];
    else if (threadIdx.x < 24) cCut[threadIdx.x - 16] = coef[threadIdx.x];
    __syncthreads();

    const int lane = threadIdx.x & 63;
    const int e    = blockIdx.x * 256 + threadIdx.x;   // 800000/256 exact

    const int row = ei[e];
    const int col = ei[N_EDGES + e];
    const float4 s0 = *(const float4*)(s_src + row * 8);
    const float4 s1 = *(const float4*)(s_src + row * 8 + 4);
    const float4 d0 = *(const float4*)(s_dst + col * 8);
    const float4 d1 = *(const float4*)(s_dst + col * 8 + 4);
    float t[8] = { s0.x + d0.x, s0.y + d0.y, s0.z + d0.z, s0.w + d0.w,
                   s1.x + d1.x, s1.y + d1.y, s1.z + d1.z, s1.w + d1.w };
    bool pass = false;
    float w[8];
    #pragma unroll
    for (int h = 0; h < 8; ++h) {
        t[h] = t[h] > 0.f ? t[h] : 0.01f * t[h];
        pass |= (t[h] >= cCut[h]);
    }
    if (pass) {
        #pragma unroll
        for (int h = 0; h < 8; ++h)
            w[h] = __expf(t[h] - cM[h]) * cC[h];
    }

    unsigned long long mask = __ballot(pass);
    while (mask) {
        const int src = (int)__builtin_ctzll(mask);
        mask &= mask - 1;
        const int rb = __shfl(row, src);
        const int cb = __shfl(col, src);
        const float* wc = Wh + (size_t)cb * NCOL + lane;
        float acc = 0.f;
        #pragma unroll
        for (int h = 0; h < 8; ++h)
            acc += __shfl(w[h], src) * wc[h * 64];
        atomicAdd(out + (size_t)rb * OUT_DIM + lane, acc);
    }
}

// ---------------------------------------------------------------------------
extern "C" void kernel_launch(void* const* d_in, const int* in_sizes, int n_in,
                              void* d_out, int out_size, void* d_ws, size_t ws_size,
                              hipStream_t stream)
{
    const float* x    = (const float*)d_in[0];
    const int*   ei   = (const int*)  d_in[1];
    const float* W    = (const float*)d_in[2];
    const float* b    = (const float*)d_in[3];
    const float* a    = (const float*)d_in[4];
    const float* gate = (const float*)d_in[5];
    float* out = (float*)d_out;

    // workspace layout (bytes, 16B-aligned), total ~157.7 MB
    char* wsb = (char*)d_ws;
    short* A2      = (short*)(wsb);                  // 50000*512*2 = 51,200,000
    float* Wh      = (float*)(wsb + 51200000);       // 50000*512*4 = 102,400,000
    short* Bt      = (short*)(wsb + 153600000);      // 512*768*2   = 786,432
    float* s_src   = (float*)(wsb + 154386432);      // 1,600,000
    float* s_dst   = (float*)(wsb + 155986432);      // 1,600,000
    float* partial = (float*)(wsb + 157586432);      // 65,536
    float* coef    = (float*)(wsb + 157651968);      // 128

    hipMemsetAsync(d_out, 0, (size_t)N_NODES * OUT_DIM * sizeof(float), stream);

    split_kernel<<<(N_NODES * 64) / 256, 256, 0, stream>>>(x, A2);
    wprep_kernel<<<512, 256, 0, stream>>>(W, Bt);

    gemm_kernel<<<dim3(4, (N_NODES + 127) / 128), 256, 0, stream>>>(
        A2, Bt, b, a, Wh, s_src, s_dst);

    edge_reduce_kernel<<<NBLK_RED, 256, 0, stream>>>(ei, s_src, s_dst, partial);
    finalize_kernel<<<1, 64, 0, stream>>>(partial, gate, coef, NBLK_RED);

    scatter_kernel<<<N_EDGES / 256, 256, 0, stream>>>(
        ei, s_src, s_dst, Wh, coef, out);
}

// Round 5
// 390.096 us; speedup vs baseline: 17.7682x; 1.0109x over previous
//
#include <hip/hip_runtime.h>

// EGA layer (GAT-like, GLOBAL per-head softmax over edges) on MI355X.
// Round 5: R4 + coalesced Wh epilogue (LDS transpose -> full-line float4
// stores; R4's scalar C-layout stores caused 5x HBM write amplification:
// WRITE_SIZE 503MB for a 102MB tensor) + XCD-aware block swizzle so the 4
// n-blocks of a row panel share one XCD's L2.
//
// Accuracy: x=xh+xl, W=Wh+Wl (bf16 RNE). xh*Wh + xl*Wh + xh*Wl leaves only
// xl*Wl (~4e-6). MFMA accumulates fp32 -> fp32-quality Wh and scores.

#define N_NODES  50000
#define N_EDGES  800000
#define IN_DIM   256
#define OUT_DIM  64
#define HEADS    8
#define NCOL     512
#define KP       768                 // split K' = 3*256
#define NBLK_RED 1024
#define LN_W_EPS (-20.72326584f)     // ln(1e-9) skip threshold
#define NRB      391                 // ceil(50000/128) row blocks

typedef __bf16 bf16x8 __attribute__((ext_vector_type(8)));
typedef float  f32x4  __attribute__((ext_vector_type(4)));

__device__ __forceinline__ short f2bf(float f) {     // RNE float->bf16 bits
    unsigned u = __builtin_bit_cast(unsigned, f);
    u += 0x7fffu + ((u >> 16) & 1u);
    return (short)(u >> 16);
}
__device__ __forceinline__ float bf2f(short s) {
    unsigned u = ((unsigned)(unsigned short)s) << 16;
    return __builtin_bit_cast(float, u);
}

// ---------------------------------------------------------------------------
// split x -> A2[row][0:256]=bf16(x) (hi), A2[row][256:512]=bf16(x-hi) (lo)
// ---------------------------------------------------------------------------
__global__ __launch_bounds__(256) void split_kernel(
    const float* __restrict__ x, short* __restrict__ A2)
{
    const int g   = blockIdx.x * 256 + threadIdx.x;  // 50000*64 exact
    const int row = g >> 6;
    const int j4  = (g & 63) * 4;
    const float4 v = *(const float4*)(x + (size_t)row * IN_DIM + j4);
    short4 hi, lo;
    hi.x = f2bf(v.x); lo.x = f2bf(v.x - bf2f(hi.x));
    hi.y = f2bf(v.y); lo.y = f2bf(v.y - bf2f(hi.y));
    hi.z = f2bf(v.z); lo.z = f2bf(v.z - bf2f(hi.z));
    hi.w = f2bf(v.w); lo.w = f2bf(v.w - bf2f(hi.w));
    *(short4*)(A2 + (size_t)row * 512 + j4)       = hi;
    *(short4*)(A2 + (size_t)row * 512 + 256 + j4) = lo;
}

// ---------------------------------------------------------------------------
// Build Bt[n][k'] (n-major, 512 x 768 bf16): rows of B' = [Wh; Wh; Wl]
// ---------------------------------------------------------------------------
__global__ void wprep_kernel(const float* __restrict__ W, short* __restrict__ Bt)
{
    const int g = blockIdx.x * 256 + threadIdx.x;   // 512*256 exact
    const int n = g >> 8, d = g & 255;
    const int h = n >> 6, o = n & 63;
    const float w = W[((size_t)h * IN_DIM + d) * OUT_DIM + o];
    const short hi = f2bf(w);
    const short lo = f2bf(w - bf2f(hi));
    Bt[(size_t)n * KP + d]       = hi;
    Bt[(size_t)n * KP + 256 + d] = hi;
    Bt[(size_t)n * KP + 512 + d] = lo;
}

// ---------------------------------------------------------------------------
// MFMA GEMM, 128x128 tile, BK=64, 16x16x32 bf16, 4 waves (2x2), 4x4 mfma/wave.
// Epilogue: acc -> LDS stage (per 16-row i-slab) -> coalesced float4 Wh
// stores (full 512B rows), plus fused s_src/s_dst scores.
// 1D grid with XCD swizzle: row panel rb lives on XCD rb%8 (all 4 n-blocks).
// ---------------------------------------------------------------------------
__global__ __launch_bounds__(256) void gemm_kernel(
    const short* __restrict__ A2, const short* __restrict__ Bt,
    const float* __restrict__ b, const float* __restrict__ a,
    float* __restrict__ Wh, float* __restrict__ s_src, float* __restrict__ s_dst)
{
    __shared__ __align__(16) char smem[36864];
    short* As    = (short*)smem;                 // 128*72 shorts
    short* Bs    = (short*)(smem + 18432);       // 128*72 shorts
    float* stage = (float*)smem;                 // 32*132 floats (epilogue)

    // XCD swizzle: bid -> (rb, nb) with rb%8 == bid%8 (HW XCD id)
    const int bid = blockIdx.x;
    const int xcd = bid & 7, q = bid >> 3;
    const int nb = q & 3;
    const int rb = (q >> 2) * 8 + xcd;
    if (rb >= NRB) return;
    const int row0 = rb * 128;
    const int n0   = nb * 128;

    const int tid  = threadIdx.x;
    const int wave = tid >> 6, lane = tid & 63;
    const int wm = wave >> 1, wn = wave & 1;
    const int cl = lane & 15, quad = lane >> 4;

    f32x4 acc[4][4] = {};

    for (int k0 = 0; k0 < KP; k0 += 64) {
        const int ka = (k0 < 512) ? k0 : k0 - 512;   // [xh|xl|xh] k-mapping
        int4 av[4], bv[4];
        #pragma unroll
        for (int t = 0; t < 4; ++t) {
            const int c  = tid + t * 256;       // 1024 chunks of 8 bf16
            const int r  = c >> 3;
            const int o8 = (c & 7) * 8;
            int ra = row0 + r; if (ra > N_NODES - 1) ra = N_NODES - 1;
            av[t] = *(const int4*)(A2 + (size_t)ra * 512 + ka + o8);
            bv[t] = *(const int4*)(Bt + (size_t)(n0 + r) * KP + k0 + o8);
        }
        __syncthreads();                         // protect prior LDS reads
        #pragma unroll
        for (int t = 0; t < 4; ++t) {
            const int c  = tid + t * 256;
            const int r  = c >> 3;
            const int o8 = (c & 7) * 8;
            *(int4*)(&As[r * 72 + o8]) = av[t];
            *(int4*)(&Bs[r * 72 + o8]) = bv[t];
        }
        __syncthreads();
        #pragma unroll
        for (int ks = 0; ks < 64; ks += 32) {
            bf16x8 af[4], bf[4];
            #pragma unroll
            for (int i = 0; i < 4; ++i)
                af[i] = *(const bf16x8*)(&As[(wm * 64 + i * 16 + cl) * 72 + ks + quad * 8]);
            #pragma unroll
            for (int j = 0; j < 4; ++j)
                bf[j] = *(const bf16x8*)(&Bs[(wn * 64 + j * 16 + cl) * 72 + ks + quad * 8]);
            #pragma unroll
            for (int i = 0; i < 4; ++i)
                #pragma unroll
                for (int j = 0; j < 4; ++j)
                    acc[i][j] = __builtin_amdgcn_mfma_f32_16x16x32_bf16(
                        af[i], bf[j], acc[i][j], 0, 0, 0);
        }
    }

    // Epilogue. Wave covers one head (64 cols). C/D: col=lane&15, row=quad*4+r.
    const int h = nb * 2 + wn;
    float bsv[4], asv[4], adv[4];
    #pragma unroll
    for (int j = 0; j < 4; ++j) {
        const int cc = j * 16 + cl;
        bsv[j] = b[h * 64 + cc];
        asv[j] = a[h * 128 + cc];
        adv[j] = a[h * 128 + 64 + cc];
    }
    #pragma unroll
    for (int i = 0; i < 4; ++i) {
        __syncthreads();   // LDS (As/Bs or previous stage) safe to overwrite
        #pragma unroll
        for (int r = 0; r < 4; ++r) {
            float ps = 0.f, pd = 0.f;
            #pragma unroll
            for (int j = 0; j < 4; ++j) {
                const float o = acc[i][j][r] + bsv[j];
                stage[(wm * 16 + quad * 4 + r) * 132 + wn * 64 + j * 16 + cl] = o;
                ps += o * asv[j];
                pd += o * adv[j];
            }
            #pragma unroll
            for (int m = 1; m < 16; m <<= 1) {
                ps += __shfl_xor(ps, m);
                pd += __shfl_xor(pd, m);
            }
            const int row = row0 + wm * 64 + i * 16 + quad * 4 + r;
            if (cl == 0 && row < N_NODES) {
                s_src[row * 8 + h] = ps;
                s_dst[row * 8 + h] = pd;
            }
        }
        __syncthreads();
        // coalesced store: 32 rows x 128 cols, full 512B per row
        #pragma unroll
        for (int s = 0; s < 4; ++s) {
            const int idx  = tid + s * 256;
            const int lrow = idx >> 5;          // 0..31
            const int c4   = idx & 31;          // float4 index in row
            const int grow = row0 + (lrow >> 4) * 64 + i * 16 + (lrow & 15);
            if (grow < N_NODES)
                *(float4*)(Wh + (size_t)grow * NCOL + n0 + c4 * 4) =
                    *(const float4*)(stage + lrow * 132 + c4 * 4);
        }
    }
}

// ---------------------------------------------------------------------------
// Online (max, sumexp) over all edges per head. Per-block partials.
// ---------------------------------------------------------------------------
__global__ __launch_bounds__(256) void edge_reduce_kernel(
    const int* __restrict__ ei, const float* __restrict__ s_src,
    const float* __restrict__ s_dst, float* __restrict__ partial)
{
    float m[8], l[8];
    #pragma unroll
    for (int h = 0; h < 8; ++h) { m[h] = -1e30f; l[h] = 0.f; }

    for (int e = blockIdx.x * 256 + threadIdx.x; e < N_EDGES; e += gridDim.x * 256) {
        const int row = ei[e];
        const int col = ei[N_EDGES + e];
        const float4 s0 = *(const float4*)(s_src + row * 8);
        const float4 s1 = *(const float4*)(s_src + row * 8 + 4);
        const float4 d0 = *(const float4*)(s_dst + col * 8);
        const float4 d1 = *(const float4*)(s_dst + col * 8 + 4);
        const float ev[8] = { s0.x + d0.x, s0.y + d0.y, s0.z + d0.z, s0.w + d0.w,
                              s1.x + d1.x, s1.y + d1.y, s1.z + d1.z, s1.w + d1.w };
        #pragma unroll
        for (int h = 0; h < 8; ++h) {
            float t = ev[h];
            t = t > 0.f ? t : 0.01f * t;     // leaky_relu 0.01
            if (t > m[h]) { l[h] = l[h] * __expf(m[h] - t) + 1.f; m[h] = t; }
            else          { l[h] += __expf(t - m[h]); }
        }
    }

    __shared__ float red[16][256];
    const int tid = threadIdx.x;
    #pragma unroll
    for (int h = 0; h < 8; ++h) { red[h][tid] = m[h]; red[8 + h][tid] = l[h]; }
    __syncthreads();
    for (int s = 128; s > 0; s >>= 1) {
        if (tid < s) {
            #pragma unroll
            for (int h = 0; h < 8; ++h) {
                float mo = red[h][tid + s], lo = red[8 + h][tid + s];
                float mm = red[h][tid],     ll = red[8 + h][tid];
                if (mo > mm) { ll = ll * __expf(mm - mo) + lo; mm = mo; }
                else         { ll += lo * __expf(mo - mm); }
                red[h][tid] = mm; red[8 + h][tid] = ll;
            }
        }
        __syncthreads();
    }
    if (tid == 0) {
        #pragma unroll
        for (int h = 0; h < 8; ++h) {
            partial[blockIdx.x * 16 + h]     = red[h][0];
            partial[blockIdx.x * 16 + 8 + h] = red[8 + h][0];
        }
    }
}

// ---------------------------------------------------------------------------
// Merge partials. coef[h]=M_h, coef[8+h]=g_h/L_h, coef[16+h]=skip cutoff.
// ---------------------------------------------------------------------------
__global__ void finalize_kernel(const float* __restrict__ partial,
                                const float* __restrict__ gate,
                                float* __restrict__ coef, int nblk)
{
    const int t = threadIdx.x;           // 64 threads: h = t&7, chunk j = t>>3
    const int h = t & 7;
    const int j = t >> 3;
    float m = -1e30f, l = 0.f;
    for (int bk = j; bk < nblk; bk += 8) {
        const float mb = partial[bk * 16 + h];
        const float lb = partial[bk * 16 + 8 + h];
        if (mb > m) { l = l * __expf(m - mb) + lb; m = mb; }
        else        { l += lb * __expf(mb - m); }
    }
    #pragma unroll
    for (int s = 8; s < 64; s <<= 1) {
        const float mo = __shfl_xor(m, s);
        const float lo = __shfl_xor(l, s);
        if (mo > m) { l = l * __expf(m - mo) + lo; m = mo; }
        else        { l += lo * __expf(mo - m); }
    }
    if (j == 0) {
        float gm = gate[0];
        for (int i = 1; i < 8; ++i) gm = fmaxf(gm, gate[i]);
        float gs = 0.f;
        for (int i = 0; i < 8; ++i) gs += __expf(gate[i] - gm);
        const float g = __expf(gate[h] - gm) / gs;
        const float C = g / l;
        coef[h]      = m;
        coef[8 + h]  = C;
        coef[16 + h] = m + LN_W_EPS - __logf(C);   // t >= cut  <=>  w >= eps
    }
}

// ---------------------------------------------------------------------------
// Thresholded scatter (R2-proven). One thread per edge for the score test;
// passing edges processed wave-cooperatively (lane = output dim o).
// ---------------------------------------------------------------------------
__global__ __launch_bounds__(256) void scatter_kernel(
    const int* __restrict__ ei, const float* __restrict__ s_src,
    const float* __restrict__ s_dst, const float* __restrict__ Wh,
    const float* __restrict__ coef, float* __restrict__ out)
{
    __shared__ float cM[8], cC[8], cCut[8];
    if (threadIdx.x < 8)       cM[threadIdx.x]        = coef[threadIdx.x];
    else if (threadIdx.x < 16) cC[threadIdx.x - 8]    = coef[threadIdx.x];
    else if (threadIdx.x < 24) cCut[threadIdx.x - 16] = coef[threadIdx.x];
    __syncthreads();

    const int lane = threadIdx.x & 63;
    const int e    = blockIdx.x * 256 + threadIdx.x;   // 800000/256 exact

    const int row = ei[e];
    const int col = ei[N_EDGES + e];
    const float4 s0 = *(const float4*)(s_src + row * 8);
    const float4 s1 = *(const float4*)(s_src + row * 8 + 4);
    const float4 d0 = *(const float4*)(s_dst + col * 8);
    const float4 d1 = *(const float4*)(s_dst + col * 8 + 4);
    float t[8] = { s0.x + d0.x, s0.y + d0.y, s0.z + d0.z, s0.w + d0.w,
                   s1.x + d1.x, s1.y + d1.y, s1.z + d1.z, s1.w + d1.w };
    bool pass = false;
    float w[8];
    #pragma unroll
    for (int h = 0; h < 8; ++h) {
        t[h] = t[h] > 0.f ? t[h] : 0.01f * t[h];
        pass |= (t[h] >= cCut[h]);
    }
    if (pass) {
        #pragma unroll
        for (int h = 0; h < 8; ++h)
            w[h] = __expf(t[h] - cM[h]) * cC[h];
    }

    unsigned long long mask = __ballot(pass);
    while (mask) {
        const int src = (int)__builtin_ctzll(mask);
        mask &= mask - 1;
        const int rb = __shfl(row, src);
        const int cb = __shfl(col, src);
        const float* wc = Wh + (size_t)cb * NCOL + lane;
        float acc = 0.f;
        #pragma unroll
        for (int h = 0; h < 8; ++h)
            acc += __shfl(w[h], src) * wc[h * 64];
        atomicAdd(out + (size_t)rb * OUT_DIM + lane, acc);
    }
}

// ---------------------------------------------------------------------------
extern "C" void kernel_launch(void* const* d_in, const int* in_sizes, int n_in,
                              void* d_out, int out_size, void* d_ws, size_t ws_size,
                              hipStream_t stream)
{
    const float* x    = (const float*)d_in[0];
    const int*   ei   = (const int*)  d_in[1];
    const float* W    = (const float*)d_in[2];
    const float* b    = (const float*)d_in[3];
    const float* a    = (const float*)d_in[4];
    const float* gate = (const float*)d_in[5];
    float* out = (float*)d_out;

    // workspace layout (bytes, 16B-aligned), total ~157.7 MB
    char* wsb = (char*)d_ws;
    short* A2      = (short*)(wsb);                  // 50000*512*2 = 51,200,000
    float* Wh      = (float*)(wsb + 51200000);       // 50000*512*4 = 102,400,000
    short* Bt      = (short*)(wsb + 153600000);      // 512*768*2   = 786,432
    float* s_src   = (float*)(wsb + 154386432);      // 1,600,000
    float* s_dst   = (float*)(wsb + 155986432);      // 1,600,000
    float* partial = (float*)(wsb + 157586432);      // 65,536
    float* coef    = (float*)(wsb + 157651968);      // 128

    hipMemsetAsync(d_out, 0, (size_t)N_NODES * OUT_DIM * sizeof(float), stream);

    split_kernel<<<(N_NODES * 64) / 256, 256, 0, stream>>>(x, A2);
    wprep_kernel<<<512, 256, 0, stream>>>(W, Bt);

    // 1D swizzled grid: 8 XCD slots x 4 n-blocks x ceil(391/8) row groups
    gemm_kernel<<<8 * 4 * ((NRB + 7) / 8), 256, 0, stream>>>(
        A2, Bt, b, a, Wh, s_src, s_dst);

    edge_reduce_kernel<<<NBLK_RED, 256, 0, stream>>>(ei, s_src, s_dst, partial);
    finalize_kernel<<<1, 64, 0, stream>>>(partial, gate, coef, NBLK_RED);

    scatter_kernel<<<N_EDGES / 256, 256, 0, stream>>>(
        ei, s_src, s_dst, Wh, coef, out);
}